// Round 13
// baseline (217.515 us; speedup 1.0000x reference)
//
#include <hip/hip_runtime.h>
#include <cstdint>

#define HW 4096
#define NC 256
#define CI 128
#define NB 16
#define MP 1024

typedef __bf16 bfv8 __attribute__((ext_vector_type(8)));
typedef float f32x16 __attribute__((ext_vector_type(16)));

__device__ __forceinline__ uint32_t bfr(float x) {
    uint32_t u = __float_as_uint(x);
    return (u + 0x7fffu + ((u >> 16) & 1u)) >> 16;
}
__device__ __forceinline__ uint32_t pkbf(float a, float b) {
    return bfr(a) | (bfr(b) << 16);
}
__device__ __forceinline__ float b2f_lo(uint32_t u) { return __uint_as_float(u << 16); }
__device__ __forceinline__ float b2f_hi(uint32_t u) { return __uint_as_float(u & 0xffff0000u); }

// cast 4 weight tensors (each 32768 f32) to bf16
__global__ void k_castw(const float* __restrict__ a, const float* __restrict__ b,
                        const float* __restrict__ c, const float* __restrict__ d,
                        ushort* __restrict__ dst) {
    const float* srcs[4] = {a, b, c, d};
    const float* s = srcs[blockIdx.y];
    int i = (blockIdx.x * 256 + threadIdx.x) * 8;
    float4 v0 = *(const float4*)(s + i);
    float4 v1 = *(const float4*)(s + i + 4);
    uint4 o;
    o.x = pkbf(v0.x, v0.y); o.y = pkbf(v0.z, v0.w);
    o.z = pkbf(v1.x, v1.y); o.w = pkbf(v1.z, v1.w);
    *(uint4*)(dst + (size_t)blockIdx.y * 32768 + i) = o;
}

// MFMA 1x1 conv (theta): in f32 [B][256][4096], wbf [128][256] bf16 -> outT [B][4096][128] bf16
template<int O_TILE, int NT>
__global__ __launch_bounds__(256) void k_conv_mfma(
        const float* __restrict__ in, const ushort* __restrict__ wbf,
        const float* __restrict__ bias0, const float* __restrict__ bias1,
        ushort* __restrict__ outT) {
    __shared__ ushort xs[NT * 256];
    const int t = threadIdx.x;
    constexpr int tilesPerB = 4096 / NT;
    const int b = blockIdx.x / tilesPerB;
    const int n0 = (blockIdx.x % tilesPerB) * NT;
    const float* inb = in + ((size_t)b * 256) * 4096 + n0;

    constexpr int RPP = 1024 / NT;
    const int c0 = t % RPP, q = t / RPP;
    #pragma unroll
    for (int p = 0; p < 256 / RPP; p++) {
        int c = c0 + p * RPP;
        float4 v = *(const float4*)(inb + (size_t)c * 4096 + q * 4);
        #pragma unroll
        for (int j = 0; j < 4; j++) {
            int n = q * 4 + j;
            xs[n * 256 + (c ^ ((n & 7) << 3))] = (ushort)bfr((&v.x)[j]);
        }
    }
    __syncthreads();

    const int lane = t & 63, w = t >> 6;
    const int ln = lane & 31, hi = lane >> 5;
    int ob0, nb0;
    if (O_TILE == 256) { ob0 = w * 2; nb0 = 0; }
    else               { ob0 = (w & 1) * 2; nb0 = (w >> 1) * 2; }

    f32x16 acc[2][2];
    #pragma unroll
    for (int i = 0; i < 2; i++)
        #pragma unroll
        for (int j = 0; j < 2; j++)
            #pragma unroll
            for (int k = 0; k < 16; k++) acc[i][j][k] = 0.f;

    const ushort* wr0 = wbf + (size_t)(ob0 * 32 + ln) * 256 + hi * 8;
    const ushort* wr1 = wr0 + 32 * 256;
    const int nr0 = nb0 * 32 + ln, nr1 = nr0 + 32;
    const int sw0 = (nr0 & 7) << 3, sw1 = (nr1 & 7) << 3;

    #pragma unroll 4
    for (int ks = 0; ks < 16; ks++) {
        int k = ks * 16 + hi * 8;
        bfv8 wf0 = *(const bfv8*)(wr0 + ks * 16);
        bfv8 wf1 = *(const bfv8*)(wr1 + ks * 16);
        bfv8 x0 = *(const bfv8*)&xs[nr0 * 256 + (k ^ sw0)];
        bfv8 x1 = *(const bfv8*)&xs[nr1 * 256 + (k ^ sw1)];
        acc[0][0] = __builtin_amdgcn_mfma_f32_32x32x16_bf16(wf0, x0, acc[0][0], 0, 0, 0);
        acc[0][1] = __builtin_amdgcn_mfma_f32_32x32x16_bf16(wf0, x1, acc[0][1], 0, 0, 0);
        acc[1][0] = __builtin_amdgcn_mfma_f32_32x32x16_bf16(wf1, x0, acc[1][0], 0, 0, 0);
        acc[1][1] = __builtin_amdgcn_mfma_f32_32x32x16_bf16(wf1, x1, acc[1][1], 0, 0, 0);
    }

    #pragma unroll
    for (int oi = 0; oi < 2; oi++) {
        int obb = (ob0 + oi) * 32;
        #pragma unroll
        for (int grp = 0; grp < 4; grp++) {
            int og = obb + grp * 8 + hi * 4;
            const float* bp = (O_TILE == 256 && og >= 128) ? bias1 : bias0;
            float4 bv = *(const float4*)&bp[og & 127];
            #pragma unroll
            for (int ni = 0; ni < 2; ni++) {
                int n = n0 + (nb0 + ni) * 32 + ln;
                float r0 = acc[oi][ni][grp * 4 + 0] + bv.x;
                float r1 = acc[oi][ni][grp * 4 + 1] + bv.y;
                float r2 = acc[oi][ni][grp * 4 + 2] + bv.z;
                float r3 = acc[oi][ni][grp * 4 + 3] + bv.w;
                uint2 pk;
                pk.x = pkbf(r0, r1); pk.y = pkbf(r2, r3);
                *(uint2*)&outT[((size_t)b * 4096 + n) * O_TILE + og] = pk;
            }
        }
    }
}

// fused phi/g conv + 2x2 maxpool: y f32 [B][256][4096], wbf [256][256] bf16
// -> phiT [B][1024][128] bf16, gout [B][128][1024] bf16. One block = one pooled row (r).
__global__ __launch_bounds__(512) void k_convpool(
        const float* __restrict__ in, const ushort* __restrict__ wbf,
        const float* __restrict__ bias0, const float* __restrict__ bias1,
        ushort* __restrict__ phiT, ushort* __restrict__ gout) {
    __shared__ char lds[65536];
    ushort* xs = (ushort*)lds;
    const int t = threadIdx.x;
    const int b = blockIdx.x >> 5;
    const int r = blockIdx.x & 31;
    const int n0 = r * 128;
    const float* inb = in + ((size_t)b * 256) * 4096 + n0;

    {
        const int c0 = t & 7, qq = t >> 3;
        const int ch = qq >> 5, n4 = (qq & 31) * 4;
        #pragma unroll
        for (int p = 0; p < 16; p++) {
            int c = c0 + ch * 8 + p * 16;
            float4 v = *(const float4*)(inb + (size_t)c * 4096 + n4);
            #pragma unroll
            for (int j = 0; j < 4; j++) {
                int n = n4 + j;
                xs[n * 256 + (c ^ ((n & 7) << 3))] = (ushort)bfr((&v.x)[j]);
            }
        }
    }
    __syncthreads();

    const int lane = t & 63, w = t >> 6;
    const int ln = lane & 31, hi = lane >> 5;
    const int ob0 = (w & 3) * 2;
    const int nb0 = (w >> 2) * 2;
    const int lr = nb0 >> 1;

    f32x16 acc[2][2];
    #pragma unroll
    for (int i = 0; i < 2; i++)
        #pragma unroll
        for (int j = 0; j < 2; j++)
            #pragma unroll
            for (int k = 0; k < 16; k++) acc[i][j][k] = 0.f;

    const ushort* wr0 = wbf + (size_t)(ob0 * 32 + ln) * 256 + hi * 8;
    const ushort* wr1 = wr0 + 32 * 256;
    const int nr0 = nb0 * 32 + ln, nr1 = nr0 + 32;
    const int sw0 = (nr0 & 7) << 3, sw1 = (nr1 & 7) << 3;

    #pragma unroll 4
    for (int ks = 0; ks < 16; ks++) {
        int k = ks * 16 + hi * 8;
        bfv8 wf0 = *(const bfv8*)(wr0 + ks * 16);
        bfv8 wf1 = *(const bfv8*)(wr1 + ks * 16);
        bfv8 x0 = *(const bfv8*)&xs[nr0 * 256 + (k ^ sw0)];
        bfv8 x1 = *(const bfv8*)&xs[nr1 * 256 + (k ^ sw1)];
        acc[0][0] = __builtin_amdgcn_mfma_f32_32x32x16_bf16(wf0, x0, acc[0][0], 0, 0, 0);
        acc[0][1] = __builtin_amdgcn_mfma_f32_32x32x16_bf16(wf0, x1, acc[0][1], 0, 0, 0);
        acc[1][0] = __builtin_amdgcn_mfma_f32_32x32x16_bf16(wf1, x0, acc[1][0], 0, 0, 0);
        acc[1][1] = __builtin_amdgcn_mfma_f32_32x32x16_bf16(wf1, x1, acc[1][1], 0, 0, 0);
    }

    __syncthreads();
    float* poolreg = (float*)lds + lr * 8192;

    #pragma unroll
    for (int oi = 0; oi < 2; oi++) {
        #pragma unroll
        for (int grp = 0; grp < 4; grp++) {
            int og = (ob0 + oi) * 32 + grp * 8 + hi * 4;
            const float* bp = (og >= 128) ? bias1 : bias0;
            float4 bv = *(const float4*)&bp[og & 127];
            #pragma unroll
            for (int ni = 0; ni < 2; ni++) {
                #pragma unroll
                for (int j = 0; j < 4; j++) {
                    float v = acc[oi][ni][grp * 4 + j] + (&bv.x)[j];
                    float hm = fmaxf(v, __shfl_xor(v, 1, 64));
                    if ((ln & 1) == 0) {
                        int o = og + j;
                        poolreg[(o << 5) + ni * 16 + (ln >> 1)] = hm;
                    }
                }
            }
        }
    }
    __syncthreads();

    const float* p0 = (const float*)lds;
    const float* p1 = (const float*)lds + 8192;
    {
        int m = t >> 4, ci8 = (t & 15) * 8;
        uint32_t pk4[4];
        #pragma unroll
        for (int jp = 0; jp < 4; jp++) {
            int o0 = ci8 + jp * 2;
            float f0 = fmaxf(p0[(o0 << 5) + m], p1[(o0 << 5) + m]);
            float f1 = fmaxf(p0[((o0 + 1) << 5) + m], p1[((o0 + 1) << 5) + m]);
            pk4[jp] = pkbf(f0, f1);
        }
        *(uint4*)&phiT[((size_t)b * MP + r * 32 + m) * CI + ci8] =
            make_uint4(pk4[0], pk4[1], pk4[2], pk4[3]);
    }
    {
        int ci = t >> 2, mq = (t & 3) * 8;
        int o = 128 + ci;
        uint32_t pk4[4];
        #pragma unroll
        for (int jp = 0; jp < 4; jp++) {
            int mm = mq + jp * 2;
            float f0 = fmaxf(p0[(o << 5) + mm], p1[(o << 5) + mm]);
            float f1 = fmaxf(p0[(o << 5) + mm + 1], p1[(o << 5) + mm + 1]);
            pk4[jp] = pkbf(f0, f1);
        }
        *(uint4*)&gout[((size_t)b * CI + ci) * MP + r * 32 + mq] =
            make_uint4(pk4[0], pk4[1], pk4[2], pk4[3]);
    }
}

// flash attention, 4 waves = 4 q-groups (128 q/block), grid 512 -> 2 blocks/CU,
// double-buffered LDS tiles (32KB x 2), one barrier per iter, loads prefetched.
// Max-free softmax (scores bounded).
__global__ __launch_bounds__(256, 2) void k_attn_mfma(
        const ushort* __restrict__ thetaT, const ushort* __restrict__ phiT,
        const ushort* __restrict__ gmat, ushort* __restrict__ zout) {
    __shared__ char lds[65536];
    const int t = threadIdx.x;
    const int w = t >> 6, lane = t & 63;
    const int nq = lane & 31, hi = lane >> 5;
    const int b = blockIdx.x >> 5;
    const int q0 = (blockIdx.x & 31) << 7;     // 128 queries per block

    // ---- stage theta [128 q][128 c] bf16 (transient in buf0 region), swizzle slot ^= row&15 ----
    {
        int row = t >> 1, s0 = (t & 1) * 8;
        const uint4* src = (const uint4*)(thetaT + ((size_t)b * HW + q0 + row) * CI) + s0;
        uint4* dstrow = (uint4*)(lds + row * 256);
        int rsw = row & 15;
        #pragma unroll
        for (int j = 0; j < 8; j++) {
            uint4 v = src[j];
            dstrow[(s0 + j) ^ rsw] = v;
        }
    }
    __syncthreads();
    bfv8 qf[8];
    {
        int row = w * 32 + nq;       // (w*32)&15 == 0 -> rsw == nq&15
        int rsw = nq & 15;
        #pragma unroll
        for (int ks = 0; ks < 8; ks++) {
            qf[ks] = *(const bfv8*)(lds + row * 256 + (((ks * 2 + hi) ^ rsw) << 4));
        }
    }
    __syncthreads();   // theta region dead; buffers may be written

    f32x16 zacc[4];
    #pragma unroll
    for (int ct = 0; ct < 4; ct++)
        #pragma unroll
        for (int i = 0; i < 16; i++) zacc[ct][i] = 0.f;
    float run_sum = 0.f;

    // staging roles: threads 0..127 stage phi tile [64 m][128 c] (16KB),
    // threads 128..255 stage g tile [128 c][64 m] (16KB). 8 x uint4 per thread (monolithic).
    const int kind = t >> 7;       // 0 = phi, 1 = g
    const int tt = t & 127;
    const int prow = tt >> 1, ps0 = (tt & 1) * 8;   // phi: 2 threads/row
    const int grow_i = tt;                           // g: 1 thread/row (8 uint4 = whole row)

    const int rswp = nq & 15;
    const int rswg = nq & 7;

    auto issue_loads = [&](int it, uint4* pf) {
        if (kind == 0) {
            const uint4* src = (const uint4*)(phiT + ((size_t)b * MP + it * 64 + prow) * CI) + ps0;
            #pragma unroll
            for (int j = 0; j < 8; j++) pf[j] = src[j];
        } else {
            const uint4* src = (const uint4*)(gmat + ((size_t)b * CI + grow_i) * MP + it * 64);
            #pragma unroll
            for (int j = 0; j < 8; j++) pf[j] = src[j];
        }
    };
    auto write_tile = [&](int buf, const uint4* pf) {
        if (kind == 0) {
            uint4* dstrow = (uint4*)(lds + buf * 32768 + prow * 256);
            int rsw = prow & 15;
            #pragma unroll
            for (int j = 0; j < 8; j++) dstrow[(ps0 + j) ^ rsw] = pf[j];
        } else {
            uint4* dstrow = (uint4*)(lds + buf * 32768 + 16384 + grow_i * 128);
            int rsw = grow_i & 7;
            #pragma unroll
            for (int j = 0; j < 8; j++) dstrow[j ^ rsw] = pf[j];
        }
    };

    // prologue: stage tile 0 into buf0
    {
        uint4 pf[8];
        issue_loads(0, pf);
        write_tile(0, pf);
    }
    __syncthreads();

    for (int it = 0; it < 16; it++) {
        uint4 pf[8];
        if (it < 15) issue_loads(it + 1, pf);   // in flight during compute

        const char* phiB = lds + (it & 1) * 32768;
        const char* gB   = phiB + 16384;

        // ---- QK^T ----
        f32x16 sA, sB;
        #pragma unroll
        for (int i = 0; i < 16; i++) { sA[i] = 0.f; sB[i] = 0.f; }
        __builtin_amdgcn_s_setprio(1);
        #pragma unroll
        for (int ks = 0; ks < 8; ks++) {
            int slot = ks * 2 + hi;
            bfv8 a0 = *(const bfv8*)(phiB + nq * 256 + ((slot ^ rswp) << 4));
            bfv8 a1 = *(const bfv8*)(phiB + (32 + nq) * 256 + ((slot ^ rswp) << 4));
            sA = __builtin_amdgcn_mfma_f32_32x32x16_bf16(a0, qf[ks], sA, 0, 0, 0);
            sB = __builtin_amdgcn_mfma_f32_32x32x16_bf16(a1, qf[ks], sB, 0, 0, 0);
        }
        __builtin_amdgcn_s_setprio(0);

        // ---- max-free softmax numerator ----
        float pA[16], pB[16];
        #pragma unroll
        for (int i = 0; i < 16; i++) { pA[i] = __expf(sA[i]); run_sum += pA[i]; }
        #pragma unroll
        for (int i = 0; i < 16; i++) { pB[i] = __expf(sB[i]); run_sum += pB[i]; }

        uint32_t wA[8], wB[8], tA[8], tB[8];
        #pragma unroll
        for (int j = 0; j < 8; j++) { wA[j] = pkbf(pA[2 * j], pA[2 * j + 1]); wB[j] = pkbf(pB[2 * j], pB[2 * j + 1]); }
        #pragma unroll
        for (int j = 0; j < 8; j++) { tA[j] = (uint32_t)__shfl_xor((int)wA[j], 32, 64); tB[j] = (uint32_t)__shfl_xor((int)wB[j], 32, 64); }
        bool lo = (hi == 0);
        union PU { uint32_t u[4]; bfv8 v; } p0A, p1A, p0B, p1B;
        p0A.u[0] = lo ? wA[0] : tA[2]; p0A.u[1] = lo ? wA[1] : tA[3];
        p0A.u[2] = lo ? tA[0] : wA[2]; p0A.u[3] = lo ? tA[1] : wA[3];
        p1A.u[0] = lo ? wA[4] : tA[6]; p1A.u[1] = lo ? wA[5] : tA[7];
        p1A.u[2] = lo ? tA[4] : wA[6]; p1A.u[3] = lo ? tA[5] : wA[7];
        p0B.u[0] = lo ? wB[0] : tB[2]; p0B.u[1] = lo ? wB[1] : tB[3];
        p0B.u[2] = lo ? tB[0] : wB[2]; p0B.u[3] = lo ? tB[1] : wB[3];
        p1B.u[0] = lo ? wB[4] : tB[6]; p1B.u[1] = lo ? wB[5] : tB[7];
        p1B.u[2] = lo ? tB[4] : wB[6]; p1B.u[3] = lo ? tB[5] : wB[7];

        // ---- PV ----
        __builtin_amdgcn_s_setprio(1);
        #pragma unroll
        for (int ct = 0; ct < 4; ct++) {
            const char* grw = gB + (ct * 32 + nq) * 128;
            bfv8 g0 = *(const bfv8*)(grw + (((0 * 2 + hi) ^ rswg) << 4));
            bfv8 g1 = *(const bfv8*)(grw + (((1 * 2 + hi) ^ rswg) << 4));
            bfv8 g2 = *(const bfv8*)(grw + (((2 * 2 + hi) ^ rswg) << 4));
            bfv8 g3 = *(const bfv8*)(grw + (((3 * 2 + hi) ^ rswg) << 4));
            zacc[ct] = __builtin_amdgcn_mfma_f32_32x32x16_bf16(g0, p0A.v, zacc[ct], 0, 0, 0);
            zacc[ct] = __builtin_amdgcn_mfma_f32_32x32x16_bf16(g1, p1A.v, zacc[ct], 0, 0, 0);
            zacc[ct] = __builtin_amdgcn_mfma_f32_32x32x16_bf16(g2, p0B.v, zacc[ct], 0, 0, 0);
            zacc[ct] = __builtin_amdgcn_mfma_f32_32x32x16_bf16(g3, p1B.v, zacc[ct], 0, 0, 0);
        }
        __builtin_amdgcn_s_setprio(0);

        if (it < 15) write_tile((it + 1) & 1, pf);
        __syncthreads();
    }

    // ---- epilogue: direct write ----
    float pair_sum = run_sum + __shfl_xor(run_sum, 32, 64);
    float rinv = 1.f / pair_sum;
    ushort* zr = zout + ((size_t)b * HW + q0 + w * 32 + nq) * CI;
    #pragma unroll
    for (int ct = 0; ct < 4; ct++) {
        #pragma unroll
        for (int grp = 0; grp < 4; grp++) {
            int c0 = ct * 32 + grp * 8 + hi * 4;
            uint2 pk;
            pk.x = pkbf(zacc[ct][grp * 4 + 0] * rinv, zacc[ct][grp * 4 + 1] * rinv);
            pk.y = pkbf(zacc[ct][grp * 4 + 2] * rinv, zacc[ct][grp * 4 + 3] * rinv);
            *(uint2*)(zr + c0) = pk;
        }
    }
}

// wz GEMM: z bf16 [B][4096][128], Wbf [256][128] bf16 -> wz bf16 [B][256][4096] + BN partials
__global__ __launch_bounds__(256) void k_wz_mfma(
        const ushort* __restrict__ z, const ushort* __restrict__ Wbf,
        const float* __restrict__ Wb, ushort* __restrict__ wz,
        float* __restrict__ part) {
    __shared__ ushort zs[128 * 128];
    int t = threadIdx.x;
    int mtile = blockIdx.x;
    int oh = blockIdx.y;
    int b = mtile >> 5;
    int n0 = (mtile & 31) << 7;
    const ushort* zt = z + ((size_t)b * 4096 + n0) * 128;
    #pragma unroll
    for (int it = 0; it < 8; it++) {
        int d = (it * 256 + t) * 16;
        uint4 v = *(const uint4*)((const char*)zt + d);
        int n = d >> 8;
        int widx = (n << 7) + (((d & 255) ^ ((n & 7) << 4)) >> 1);
        *(uint4*)&zs[widx] = v;
    }
    __syncthreads();
    int lane = t & 63, w = t >> 6;
    int ln = lane & 31, hi = lane >> 5;
    int wr = w >> 1, wc = w & 1;
    f32x16 acc[2][2];
    #pragma unroll
    for (int i = 0; i < 2; i++)
        #pragma unroll
        for (int j = 0; j < 2; j++)
            #pragma unroll
            for (int k = 0; k < 16; k++) acc[i][j][k] = 0.f;
    const ushort* w0 = Wbf + (size_t)(oh * 128 + wc * 64 + ln) * 128 + hi * 8;
    const ushort* w1 = w0 + 32 * 128;
    int nr0 = wr * 64 + ln, nr1 = nr0 + 32;
    int sw0 = (nr0 & 7) << 3, sw1 = (nr1 & 7) << 3;
    #pragma unroll
    for (int ks = 0; ks < 8; ks++) {
        int k = ks * 16 + hi * 8;
        bfv8 a0 = *(const bfv8*)&zs[(nr0 << 7) + (k ^ sw0)];
        bfv8 a1 = *(const bfv8*)&zs[(nr1 << 7) + (k ^ sw1)];
        bfv8 b0 = *(const bfv8*)(w0 + ks * 16);
        bfv8 b1 = *(const bfv8*)(w1 + ks * 16);
        acc[0][0] = __builtin_amdgcn_mfma_f32_32x32x16_bf16(a0, b0, acc[0][0], 0, 0, 0);
        acc[0][1] = __builtin_amdgcn_mfma_f32_32x32x16_bf16(a0, b1, acc[0][1], 0, 0, 0);
        acc[1][0] = __builtin_amdgcn_mfma_f32_32x32x16_bf16(a1, b0, acc[1][0], 0, 0, 0);
        acc[1][1] = __builtin_amdgcn_mfma_f32_32x32x16_bf16(a1, b1, acc[1][1], 0, 0, 0);
    }
    #pragma unroll
    for (int obi = 0; obi < 2; obi++) {
        int o = oh * 128 + wc * 64 + obi * 32 + ln;
        float bv = Wb[o];
        ushort* orow = wz + ((size_t)b * 256 + o) * 4096 + n0;
        float s = 0.f, qq = 0.f;
        #pragma unroll
        for (int nbi = 0; nbi < 2; nbi++) {
            #pragma unroll
            for (int grp = 0; grp < 4; grp++) {
                float vals[4];
                #pragma unroll
                for (int j = 0; j < 4; j++) {
                    float v = acc[nbi][obi][grp * 4 + j] + bv;
                    vals[j] = v;
                    s += v; qq += v * v;
                }
                int n = (wr * 2 + nbi) * 32 + grp * 8 + hi * 4;
                uint2 pk;
                pk.x = pkbf(vals[0], vals[1]);
                pk.y = pkbf(vals[2], vals[3]);
                *(uint2*)(orow + n) = pk;
            }
        }
        s += __shfl_xor(s, 32, 64);
        qq += __shfl_xor(qq, 32, 64);
        if (hi == 0) {
            float* pr = part + (size_t)(mtile * 2 + wr) * 512;
            pr[o] = s;
            pr[256 + o] = qq;
        }
    }
}

__global__ __launch_bounds__(256) void k_bnstats(const float* __restrict__ part,
        const float* __restrict__ gamma, const float* __restrict__ beta,
        float* __restrict__ ss) {
    int o = blockIdx.x, t = threadIdx.x;
    float s = 0.f, q = 0.f;
    for (int k = t; k < 1024; k += 256) {
        s += part[(size_t)k * 512 + o];
        q += part[(size_t)k * 512 + 256 + o];
    }
    #pragma unroll
    for (int d = 32; d > 0; d >>= 1) { s += __shfl_down(s, d, 64); q += __shfl_down(q, d, 64); }
    __shared__ float rs[4], rq[4];
    int wave = t >> 6, lane = t & 63;
    if (lane == 0) { rs[wave] = s; rq[wave] = q; }
    __syncthreads();
    if (t == 0) {
        float S = rs[0] + rs[1] + rs[2] + rs[3];
        float Q = rq[0] + rq[1] + rq[2] + rq[3];
        const float inv = 1.0f / 65536.0f;
        float mean = S * inv;
        float var = Q * inv - mean * mean;
        float sc = gamma[o] * rsqrtf(var + 1e-5f);
        ss[o] = sc;
        ss[NC + o] = beta[o] - mean * sc;
    }
}

// out = wz*scale + shift + x  (wz bf16, x f32 -> out f32)
__global__ void k_apply(float* __restrict__ out, const ushort* __restrict__ wz,
        const float* __restrict__ x, const float* __restrict__ ss) {
    size_t i = ((size_t)blockIdx.x * 256 + threadIdx.x) * 8;
    int o = (int)((i >> 12) & 255);
    float sc = ss[o], sh = ss[NC + o];
    uint4 wv = *(const uint4*)(wz + i);
    float4 x0 = *(const float4*)(x + i);
    float4 x1 = *(const float4*)(x + i + 4);
    float4 r0, r1;
    r0.x = b2f_lo(wv.x) * sc + sh + x0.x;
    r0.y = b2f_hi(wv.x) * sc + sh + x0.y;
    r0.z = b2f_lo(wv.y) * sc + sh + x0.z;
    r0.w = b2f_hi(wv.y) * sc + sh + x0.w;
    r1.x = b2f_lo(wv.z) * sc + sh + x1.x;
    r1.y = b2f_hi(wv.z) * sc + sh + x1.y;
    r1.z = b2f_lo(wv.w) * sc + sh + x1.z;
    r1.w = b2f_hi(wv.w) * sc + sh + x1.w;
    *(float4*)(out + i) = r0;
    *(float4*)(out + i + 4) = r1;
}

extern "C" void kernel_launch(void* const* d_in, const int* in_sizes, int n_in,
                              void* d_out, int out_size, void* d_ws, size_t ws_size,
                              hipStream_t stream) {
    const float* x       = (const float*)d_in[0];
    const float* y       = (const float*)d_in[1];
    const float* theta_w = (const float*)d_in[2];
    const float* theta_b = (const float*)d_in[3];
    const float* phi_w   = (const float*)d_in[4];
    const float* phi_b   = (const float*)d_in[5];
    const float* g_w     = (const float*)d_in[6];
    const float* g_b     = (const float*)d_in[7];
    const float* W_w     = (const float*)d_in[8];
    const float* W_b     = (const float*)d_in[9];
    const float* bn_g    = (const float*)d_in[10];
    const float* bn_b    = (const float*)d_in[11];
    float* ws  = (float*)d_ws;
    float* out = (float*)d_out;

    // ws layout (float offsets):
    //   [0,        65536)    wbf: 4x32768 bf16 weights
    //   [65536,    4259840)  thetaT bf16 [16][4096][128]   (dead after attn)
    //   [65536,    8454144)  wzbf bf16 [16][256][4096]     (written by k_wz after attn)
    //   [8454144, 12648448)  z bf16 [16][4096][128]        (attn out; DISJOINT from wzbf)
    //   [12648448,13697024)  phiT bf16 [16][1024][128]
    //   [13697024,14745600)  gbuf bf16 [16][128][1024]
    //   [14745600,15269888)  part [1024][512]
    //   [15269888,15270400)  ss
    ushort* wbf    = (ushort*)ws;
    ushort* thetaT = (ushort*)(ws + 65536);
    ushort* wzbf   = (ushort*)(ws + 65536);
    ushort* zbuf   = (ushort*)(ws + 8454144);
    ushort* phiT   = (ushort*)(ws + 12648448);
    ushort* gbuf   = (ushort*)(ws + 13697024);
    float*  part   = ws + 14745600;
    float*  ss     = ws + 15269888;

    k_castw<<<dim3(16, 4), 256, 0, stream>>>(theta_w, phi_w, g_w, W_w, wbf);

    k_conv_mfma<128, 128><<<NB * 32, 256, 0, stream>>>(x, wbf, theta_b, theta_b, thetaT);
    k_convpool<<<NB * 32, 512, 0, stream>>>(y, wbf + 32768, phi_b, g_b, phiT, gbuf);

    k_attn_mfma<<<NB * 32, 256, 0, stream>>>(thetaT, phiT, gbuf, zbuf);

    k_wz_mfma<<<dim3(NB * 32, 2), 256, 0, stream>>>(zbuf, wbf + 98304, W_b, wzbf, part);
    k_bnstats<<<256, 256, 0, stream>>>(part, bn_g, bn_b, ss);
    k_apply<<<8192, 256, 0, stream>>>(out, wzbf, x, ss);
}

// Round 14
// 180.511 us; speedup vs baseline: 1.2050x; 1.2050x over previous
//
#include <hip/hip_runtime.h>
#include <cstdint>

#define HW 4096
#define NC 256
#define CI 128
#define NB 16
#define MP 1024

typedef __bf16 bfv8 __attribute__((ext_vector_type(8)));
typedef float f32x16 __attribute__((ext_vector_type(16)));

__device__ __forceinline__ uint32_t bfr(float x) {
    uint32_t u = __float_as_uint(x);
    return (u + 0x7fffu + ((u >> 16) & 1u)) >> 16;
}
__device__ __forceinline__ uint32_t pkbf(float a, float b) {
    return bfr(a) | (bfr(b) << 16);
}
__device__ __forceinline__ float b2f_lo(uint32_t u) { return __uint_as_float(u << 16); }
__device__ __forceinline__ float b2f_hi(uint32_t u) { return __uint_as_float(u & 0xffff0000u); }

// cast 4 weight tensors (each 32768 f32) to bf16
__global__ void k_castw(const float* __restrict__ a, const float* __restrict__ b,
                        const float* __restrict__ c, const float* __restrict__ d,
                        ushort* __restrict__ dst) {
    const float* srcs[4] = {a, b, c, d};
    const float* s = srcs[blockIdx.y];
    int i = (blockIdx.x * 256 + threadIdx.x) * 8;
    float4 v0 = *(const float4*)(s + i);
    float4 v1 = *(const float4*)(s + i + 4);
    uint4 o;
    o.x = pkbf(v0.x, v0.y); o.y = pkbf(v0.z, v0.w);
    o.z = pkbf(v1.x, v1.y); o.w = pkbf(v1.z, v1.w);
    *(uint4*)(dst + (size_t)blockIdx.y * 32768 + i) = o;
}

// MFMA 1x1 conv (theta): in f32 [B][256][4096], wbf [128][256] bf16 -> outT [B][4096][128] bf16
template<int O_TILE, int NT>
__global__ __launch_bounds__(256) void k_conv_mfma(
        const float* __restrict__ in, const ushort* __restrict__ wbf,
        const float* __restrict__ bias0, const float* __restrict__ bias1,
        ushort* __restrict__ outT) {
    __shared__ ushort xs[NT * 256];
    const int t = threadIdx.x;
    constexpr int tilesPerB = 4096 / NT;
    const int b = blockIdx.x / tilesPerB;
    const int n0 = (blockIdx.x % tilesPerB) * NT;
    const float* inb = in + ((size_t)b * 256) * 4096 + n0;

    constexpr int RPP = 1024 / NT;
    const int c0 = t % RPP, q = t / RPP;
    #pragma unroll
    for (int p = 0; p < 256 / RPP; p++) {
        int c = c0 + p * RPP;
        float4 v = *(const float4*)(inb + (size_t)c * 4096 + q * 4);
        #pragma unroll
        for (int j = 0; j < 4; j++) {
            int n = q * 4 + j;
            xs[n * 256 + (c ^ ((n & 7) << 3))] = (ushort)bfr((&v.x)[j]);
        }
    }
    __syncthreads();

    const int lane = t & 63, w = t >> 6;
    const int ln = lane & 31, hi = lane >> 5;
    int ob0, nb0;
    if (O_TILE == 256) { ob0 = w * 2; nb0 = 0; }
    else               { ob0 = (w & 1) * 2; nb0 = (w >> 1) * 2; }

    f32x16 acc[2][2];
    #pragma unroll
    for (int i = 0; i < 2; i++)
        #pragma unroll
        for (int j = 0; j < 2; j++)
            #pragma unroll
            for (int k = 0; k < 16; k++) acc[i][j][k] = 0.f;

    const ushort* wr0 = wbf + (size_t)(ob0 * 32 + ln) * 256 + hi * 8;
    const ushort* wr1 = wr0 + 32 * 256;
    const int nr0 = nb0 * 32 + ln, nr1 = nr0 + 32;
    const int sw0 = (nr0 & 7) << 3, sw1 = (nr1 & 7) << 3;

    #pragma unroll 4
    for (int ks = 0; ks < 16; ks++) {
        int k = ks * 16 + hi * 8;
        bfv8 wf0 = *(const bfv8*)(wr0 + ks * 16);
        bfv8 wf1 = *(const bfv8*)(wr1 + ks * 16);
        bfv8 x0 = *(const bfv8*)&xs[nr0 * 256 + (k ^ sw0)];
        bfv8 x1 = *(const bfv8*)&xs[nr1 * 256 + (k ^ sw1)];
        acc[0][0] = __builtin_amdgcn_mfma_f32_32x32x16_bf16(wf0, x0, acc[0][0], 0, 0, 0);
        acc[0][1] = __builtin_amdgcn_mfma_f32_32x32x16_bf16(wf0, x1, acc[0][1], 0, 0, 0);
        acc[1][0] = __builtin_amdgcn_mfma_f32_32x32x16_bf16(wf1, x0, acc[1][0], 0, 0, 0);
        acc[1][1] = __builtin_amdgcn_mfma_f32_32x32x16_bf16(wf1, x1, acc[1][1], 0, 0, 0);
    }

    #pragma unroll
    for (int oi = 0; oi < 2; oi++) {
        int obb = (ob0 + oi) * 32;
        #pragma unroll
        for (int grp = 0; grp < 4; grp++) {
            int og = obb + grp * 8 + hi * 4;
            const float* bp = (O_TILE == 256 && og >= 128) ? bias1 : bias0;
            float4 bv = *(const float4*)&bp[og & 127];
            #pragma unroll
            for (int ni = 0; ni < 2; ni++) {
                int n = n0 + (nb0 + ni) * 32 + ln;
                float r0 = acc[oi][ni][grp * 4 + 0] + bv.x;
                float r1 = acc[oi][ni][grp * 4 + 1] + bv.y;
                float r2 = acc[oi][ni][grp * 4 + 2] + bv.z;
                float r3 = acc[oi][ni][grp * 4 + 3] + bv.w;
                uint2 pk;
                pk.x = pkbf(r0, r1); pk.y = pkbf(r2, r3);
                *(uint2*)&outT[((size_t)b * 4096 + n) * O_TILE + og] = pk;
            }
        }
    }
}

// fused phi/g conv + 2x2 maxpool: y f32 [B][256][4096], wbf [256][256] bf16
// -> phiT [B][1024][128] bf16, gout [B][128][1024] bf16. One block = one pooled row (r).
__global__ __launch_bounds__(512) void k_convpool(
        const float* __restrict__ in, const ushort* __restrict__ wbf,
        const float* __restrict__ bias0, const float* __restrict__ bias1,
        ushort* __restrict__ phiT, ushort* __restrict__ gout) {
    __shared__ char lds[65536];
    ushort* xs = (ushort*)lds;
    const int t = threadIdx.x;
    const int b = blockIdx.x >> 5;
    const int r = blockIdx.x & 31;
    const int n0 = r * 128;
    const float* inb = in + ((size_t)b * 256) * 4096 + n0;

    {
        const int c0 = t & 7, qq = t >> 3;
        const int ch = qq >> 5, n4 = (qq & 31) * 4;
        #pragma unroll
        for (int p = 0; p < 16; p++) {
            int c = c0 + ch * 8 + p * 16;
            float4 v = *(const float4*)(inb + (size_t)c * 4096 + n4);
            #pragma unroll
            for (int j = 0; j < 4; j++) {
                int n = n4 + j;
                xs[n * 256 + (c ^ ((n & 7) << 3))] = (ushort)bfr((&v.x)[j]);
            }
        }
    }
    __syncthreads();

    const int lane = t & 63, w = t >> 6;
    const int ln = lane & 31, hi = lane >> 5;
    const int ob0 = (w & 3) * 2;
    const int nb0 = (w >> 2) * 2;
    const int lr = nb0 >> 1;

    f32x16 acc[2][2];
    #pragma unroll
    for (int i = 0; i < 2; i++)
        #pragma unroll
        for (int j = 0; j < 2; j++)
            #pragma unroll
            for (int k = 0; k < 16; k++) acc[i][j][k] = 0.f;

    const ushort* wr0 = wbf + (size_t)(ob0 * 32 + ln) * 256 + hi * 8;
    const ushort* wr1 = wr0 + 32 * 256;
    const int nr0 = nb0 * 32 + ln, nr1 = nr0 + 32;
    const int sw0 = (nr0 & 7) << 3, sw1 = (nr1 & 7) << 3;

    #pragma unroll 4
    for (int ks = 0; ks < 16; ks++) {
        int k = ks * 16 + hi * 8;
        bfv8 wf0 = *(const bfv8*)(wr0 + ks * 16);
        bfv8 wf1 = *(const bfv8*)(wr1 + ks * 16);
        bfv8 x0 = *(const bfv8*)&xs[nr0 * 256 + (k ^ sw0)];
        bfv8 x1 = *(const bfv8*)&xs[nr1 * 256 + (k ^ sw1)];
        acc[0][0] = __builtin_amdgcn_mfma_f32_32x32x16_bf16(wf0, x0, acc[0][0], 0, 0, 0);
        acc[0][1] = __builtin_amdgcn_mfma_f32_32x32x16_bf16(wf0, x1, acc[0][1], 0, 0, 0);
        acc[1][0] = __builtin_amdgcn_mfma_f32_32x32x16_bf16(wf1, x0, acc[1][0], 0, 0, 0);
        acc[1][1] = __builtin_amdgcn_mfma_f32_32x32x16_bf16(wf1, x1, acc[1][1], 0, 0, 0);
    }

    __syncthreads();
    float* poolreg = (float*)lds + lr * 8192;

    #pragma unroll
    for (int oi = 0; oi < 2; oi++) {
        #pragma unroll
        for (int grp = 0; grp < 4; grp++) {
            int og = (ob0 + oi) * 32 + grp * 8 + hi * 4;
            const float* bp = (og >= 128) ? bias1 : bias0;
            float4 bv = *(const float4*)&bp[og & 127];
            #pragma unroll
            for (int ni = 0; ni < 2; ni++) {
                #pragma unroll
                for (int j = 0; j < 4; j++) {
                    float v = acc[oi][ni][grp * 4 + j] + (&bv.x)[j];
                    float hm = fmaxf(v, __shfl_xor(v, 1, 64));
                    if ((ln & 1) == 0) {
                        int o = og + j;
                        poolreg[(o << 5) + ni * 16 + (ln >> 1)] = hm;
                    }
                }
            }
        }
    }
    __syncthreads();

    const float* p0 = (const float*)lds;
    const float* p1 = (const float*)lds + 8192;
    {
        int m = t >> 4, ci8 = (t & 15) * 8;
        uint32_t pk4[4];
        #pragma unroll
        for (int jp = 0; jp < 4; jp++) {
            int o0 = ci8 + jp * 2;
            float f0 = fmaxf(p0[(o0 << 5) + m], p1[(o0 << 5) + m]);
            float f1 = fmaxf(p0[((o0 + 1) << 5) + m], p1[((o0 + 1) << 5) + m]);
            pk4[jp] = pkbf(f0, f1);
        }
        *(uint4*)&phiT[((size_t)b * MP + r * 32 + m) * CI + ci8] =
            make_uint4(pk4[0], pk4[1], pk4[2], pk4[3]);
    }
    {
        int ci = t >> 2, mq = (t & 3) * 8;
        int o = 128 + ci;
        uint32_t pk4[4];
        #pragma unroll
        for (int jp = 0; jp < 4; jp++) {
            int mm = mq + jp * 2;
            float f0 = fmaxf(p0[(o << 5) + mm], p1[(o << 5) + mm]);
            float f1 = fmaxf(p0[(o << 5) + mm + 1], p1[(o << 5) + mm + 1]);
            pk4[jp] = pkbf(f0, f1);
        }
        *(uint4*)&gout[((size_t)b * CI + ci) * MP + r * 32 + mq] =
            make_uint4(pk4[0], pk4[1], pk4[2], pk4[3]);
    }
}

// flash attention, 8 waves = 8 q-groups (256 q/block), single m-stream,
// double-buffered LDS tiles (32KB x 2), one barrier per iter, loads prefetched.
// Max-free softmax (scores bounded).  [R12-proven]
__global__ __launch_bounds__(512, 2) void k_attn_mfma(
        const ushort* __restrict__ thetaT, const ushort* __restrict__ phiT,
        const ushort* __restrict__ gmat, ushort* __restrict__ zout) {
    __shared__ char lds[65536];
    const int t = threadIdx.x;
    const int w = t >> 6, lane = t & 63;
    const int nq = lane & 31, hi = lane >> 5;
    const int b = blockIdx.x >> 4;
    const int q0 = (blockIdx.x & 15) << 8;     // 256 queries per block

    // ---- stage theta [256 q][128 c] bf16 into full LDS (transient), swizzle slot ^= row&15 ----
    {
        int row = t >> 1, s0 = (t & 1) * 8;
        const uint4* src = (const uint4*)(thetaT + ((size_t)b * HW + q0 + row) * CI) + s0;
        uint4* dstrow = (uint4*)(lds + row * 256);
        int rsw = row & 15;
        #pragma unroll
        for (int j = 0; j < 8; j++) {
            uint4 v = src[j];
            dstrow[(s0 + j) ^ rsw] = v;
        }
    }
    __syncthreads();
    bfv8 qf[8];
    {
        int row = w * 32 + nq;       // (w*32)&15 == 0, so rsw == nq&15
        int rsw = nq & 15;
        #pragma unroll
        for (int ks = 0; ks < 8; ks++) {
            qf[ks] = *(const bfv8*)(lds + row * 256 + (((ks * 2 + hi) ^ rsw) << 4));
        }
    }
    __syncthreads();   // theta region dead; buffers may be written

    f32x16 zacc[4];
    #pragma unroll
    for (int ct = 0; ct < 4; ct++)
        #pragma unroll
        for (int i = 0; i < 16; i++) zacc[ct][i] = 0.f;
    float run_sum = 0.f;

    // staging roles: threads 0..255 stage phi tile [64 m][128 c] (16KB),
    // threads 256..511 stage g tile [128 c][64 m] (16KB).
    const int kind = t >> 8;       // 0 = phi, 1 = g
    const int tt = t & 255;
    const int prow = tt >> 2, ps0 = (tt & 3) * 4;
    const int grow_i = tt >> 1, gs0 = (tt & 1) * 4;

    const int rswp = nq & 15;
    const int rswg = nq & 7;

    auto issue_loads = [&](int it, uint4* pf) {
        if (kind == 0) {
            const uint4* src = (const uint4*)(phiT + ((size_t)b * MP + it * 64 + prow) * CI) + ps0;
            #pragma unroll
            for (int j = 0; j < 4; j++) pf[j] = src[j];
        } else {
            const uint4* src = (const uint4*)(gmat + ((size_t)b * CI + grow_i) * MP + it * 64) + gs0;
            #pragma unroll
            for (int j = 0; j < 4; j++) pf[j] = src[j];
        }
    };
    auto write_tile = [&](int buf, const uint4* pf) {
        if (kind == 0) {
            uint4* dstrow = (uint4*)(lds + buf * 32768 + prow * 256);
            int rsw = prow & 15;
            #pragma unroll
            for (int j = 0; j < 4; j++) dstrow[(ps0 + j) ^ rsw] = pf[j];
        } else {
            uint4* dstrow = (uint4*)(lds + buf * 32768 + 16384 + grow_i * 128);
            int rsw = grow_i & 7;
            #pragma unroll
            for (int j = 0; j < 4; j++) dstrow[(gs0 + j) ^ rsw] = pf[j];
        }
    };

    // prologue: stage tile 0 into buf0
    {
        uint4 pf[4];
        issue_loads(0, pf);
        write_tile(0, pf);
    }
    __syncthreads();

    for (int it = 0; it < 16; it++) {
        uint4 pf[4];
        if (it < 15) issue_loads(it + 1, pf);   // in flight during compute

        const char* phiB = lds + (it & 1) * 32768;
        const char* gB   = phiB + 16384;

        // ---- QK^T ----
        f32x16 sA, sB;
        #pragma unroll
        for (int i = 0; i < 16; i++) { sA[i] = 0.f; sB[i] = 0.f; }
        __builtin_amdgcn_s_setprio(1);
        #pragma unroll
        for (int ks = 0; ks < 8; ks++) {
            int slot = ks * 2 + hi;
            bfv8 a0 = *(const bfv8*)(phiB + nq * 256 + ((slot ^ rswp) << 4));
            bfv8 a1 = *(const bfv8*)(phiB + (32 + nq) * 256 + ((slot ^ rswp) << 4));
            sA = __builtin_amdgcn_mfma_f32_32x32x16_bf16(a0, qf[ks], sA, 0, 0, 0);
            sB = __builtin_amdgcn_mfma_f32_32x32x16_bf16(a1, qf[ks], sB, 0, 0, 0);
        }
        __builtin_amdgcn_s_setprio(0);

        // ---- max-free softmax numerator ----
        float pA[16], pB[16];
        #pragma unroll
        for (int i = 0; i < 16; i++) { pA[i] = __expf(sA[i]); run_sum += pA[i]; }
        #pragma unroll
        for (int i = 0; i < 16; i++) { pB[i] = __expf(sB[i]); run_sum += pB[i]; }

        uint32_t wA[8], wB[8], tA[8], tB[8];
        #pragma unroll
        for (int j = 0; j < 8; j++) { wA[j] = pkbf(pA[2 * j], pA[2 * j + 1]); wB[j] = pkbf(pB[2 * j], pB[2 * j + 1]); }
        #pragma unroll
        for (int j = 0; j < 8; j++) { tA[j] = (uint32_t)__shfl_xor((int)wA[j], 32, 64); tB[j] = (uint32_t)__shfl_xor((int)wB[j], 32, 64); }
        bool lo = (hi == 0);
        union PU { uint32_t u[4]; bfv8 v; } p0A, p1A, p0B, p1B;
        p0A.u[0] = lo ? wA[0] : tA[2]; p0A.u[1] = lo ? wA[1] : tA[3];
        p0A.u[2] = lo ? tA[0] : wA[2]; p0A.u[3] = lo ? tA[1] : wA[3];
        p1A.u[0] = lo ? wA[4] : tA[6]; p1A.u[1] = lo ? wA[5] : tA[7];
        p1A.u[2] = lo ? tA[4] : wA[6]; p1A.u[3] = lo ? tA[5] : wA[7];
        p0B.u[0] = lo ? wB[0] : tB[2]; p0B.u[1] = lo ? wB[1] : tB[3];
        p0B.u[2] = lo ? tB[0] : wB[2]; p0B.u[3] = lo ? tB[1] : wB[3];
        p1B.u[0] = lo ? wB[4] : tB[6]; p1B.u[1] = lo ? wB[5] : tB[7];
        p1B.u[2] = lo ? tB[4] : wB[6]; p1B.u[3] = lo ? tB[5] : wB[7];

        // ---- PV ----
        __builtin_amdgcn_s_setprio(1);
        #pragma unroll
        for (int ct = 0; ct < 4; ct++) {
            const char* grw = gB + (ct * 32 + nq) * 128;
            bfv8 g0 = *(const bfv8*)(grw + (((0 * 2 + hi) ^ rswg) << 4));
            bfv8 g1 = *(const bfv8*)(grw + (((1 * 2 + hi) ^ rswg) << 4));
            bfv8 g2 = *(const bfv8*)(grw + (((2 * 2 + hi) ^ rswg) << 4));
            bfv8 g3 = *(const bfv8*)(grw + (((3 * 2 + hi) ^ rswg) << 4));
            zacc[ct] = __builtin_amdgcn_mfma_f32_32x32x16_bf16(g0, p0A.v, zacc[ct], 0, 0, 0);
            zacc[ct] = __builtin_amdgcn_mfma_f32_32x32x16_bf16(g1, p1A.v, zacc[ct], 0, 0, 0);
            zacc[ct] = __builtin_amdgcn_mfma_f32_32x32x16_bf16(g2, p0B.v, zacc[ct], 0, 0, 0);
            zacc[ct] = __builtin_amdgcn_mfma_f32_32x32x16_bf16(g3, p1B.v, zacc[ct], 0, 0, 0);
        }
        __builtin_amdgcn_s_setprio(0);

        if (it < 15) write_tile((it + 1) & 1, pf);
        __syncthreads();
    }

    // ---- epilogue: direct write (R3-proven layout) ----
    float pair_sum = run_sum + __shfl_xor(run_sum, 32, 64);
    float rinv = 1.f / pair_sum;
    ushort* zr = zout + ((size_t)b * HW + q0 + w * 32 + nq) * CI;
    #pragma unroll
    for (int ct = 0; ct < 4; ct++) {
        #pragma unroll
        for (int grp = 0; grp < 4; grp++) {
            int c0 = ct * 32 + grp * 8 + hi * 4;
            uint2 pk;
            pk.x = pkbf(zacc[ct][grp * 4 + 0] * rinv, zacc[ct][grp * 4 + 1] * rinv);
            pk.y = pkbf(zacc[ct][grp * 4 + 2] * rinv, zacc[ct][grp * 4 + 3] * rinv);
            *(uint2*)(zr + c0) = pk;
        }
    }
}

// wz GEMM: z bf16 [B][4096][128], Wbf [256][128] bf16 -> wz bf16 [B][256][4096] + BN partials
__global__ __launch_bounds__(256) void k_wz_mfma(
        const ushort* __restrict__ z, const ushort* __restrict__ Wbf,
        const float* __restrict__ Wb, ushort* __restrict__ wz,
        float* __restrict__ part) {
    __shared__ ushort zs[128 * 128];
    int t = threadIdx.x;
    int mtile = blockIdx.x;
    int oh = blockIdx.y;
    int b = mtile >> 5;
    int n0 = (mtile & 31) << 7;
    const ushort* zt = z + ((size_t)b * 4096 + n0) * 128;
    #pragma unroll
    for (int it = 0; it < 8; it++) {
        int d = (it * 256 + t) * 16;
        uint4 v = *(const uint4*)((const char*)zt + d);
        int n = d >> 8;
        int widx = (n << 7) + (((d & 255) ^ ((n & 7) << 4)) >> 1);
        *(uint4*)&zs[widx] = v;
    }
    __syncthreads();
    int lane = t & 63, w = t >> 6;
    int ln = lane & 31, hi = lane >> 5;
    int wr = w >> 1, wc = w & 1;
    f32x16 acc[2][2];
    #pragma unroll
    for (int i = 0; i < 2; i++)
        #pragma unroll
        for (int j = 0; j < 2; j++)
            #pragma unroll
            for (int k = 0; k < 16; k++) acc[i][j][k] = 0.f;
    const ushort* w0 = Wbf + (size_t)(oh * 128 + wc * 64 + ln) * 128 + hi * 8;
    const ushort* w1 = w0 + 32 * 128;
    int nr0 = wr * 64 + ln, nr1 = nr0 + 32;
    int sw0 = (nr0 & 7) << 3, sw1 = (nr1 & 7) << 3;
    #pragma unroll
    for (int ks = 0; ks < 8; ks++) {
        int k = ks * 16 + hi * 8;
        bfv8 a0 = *(const bfv8*)&zs[(nr0 << 7) + (k ^ sw0)];
        bfv8 a1 = *(const bfv8*)&zs[(nr1 << 7) + (k ^ sw1)];
        bfv8 b0 = *(const bfv8*)(w0 + ks * 16);
        bfv8 b1 = *(const bfv8*)(w1 + ks * 16);
        acc[0][0] = __builtin_amdgcn_mfma_f32_32x32x16_bf16(a0, b0, acc[0][0], 0, 0, 0);
        acc[0][1] = __builtin_amdgcn_mfma_f32_32x32x16_bf16(a0, b1, acc[0][1], 0, 0, 0);
        acc[1][0] = __builtin_amdgcn_mfma_f32_32x32x16_bf16(a1, b0, acc[1][0], 0, 0, 0);
        acc[1][1] = __builtin_amdgcn_mfma_f32_32x32x16_bf16(a1, b1, acc[1][1], 0, 0, 0);
    }
    #pragma unroll
    for (int obi = 0; obi < 2; obi++) {
        int o = oh * 128 + wc * 64 + obi * 32 + ln;
        float bv = Wb[o];
        ushort* orow = wz + ((size_t)b * 256 + o) * 4096 + n0;
        float s = 0.f, qq = 0.f;
        #pragma unroll
        for (int nbi = 0; nbi < 2; nbi++) {
            #pragma unroll
            for (int grp = 0; grp < 4; grp++) {
                float vals[4];
                #pragma unroll
                for (int j = 0; j < 4; j++) {
                    float v = acc[nbi][obi][grp * 4 + j] + bv;
                    vals[j] = v;
                    s += v; qq += v * v;
                }
                int n = (wr * 2 + nbi) * 32 + grp * 8 + hi * 4;
                uint2 pk;
                pk.x = pkbf(vals[0], vals[1]);
                pk.y = pkbf(vals[2], vals[3]);
                *(uint2*)(orow + n) = pk;
            }
        }
        s += __shfl_xor(s, 32, 64);
        qq += __shfl_xor(qq, 32, 64);
        if (hi == 0) {
            float* pr = part + (size_t)(mtile * 2 + wr) * 512;
            pr[o] = s;
            pr[256 + o] = qq;
        }
    }
}

__global__ __launch_bounds__(256) void k_bnstats(const float* __restrict__ part,
        const float* __restrict__ gamma, const float* __restrict__ beta,
        float* __restrict__ ss) {
    int o = blockIdx.x, t = threadIdx.x;
    float s = 0.f, q = 0.f;
    for (int k = t; k < 1024; k += 256) {
        s += part[(size_t)k * 512 + o];
        q += part[(size_t)k * 512 + 256 + o];
    }
    #pragma unroll
    for (int d = 32; d > 0; d >>= 1) { s += __shfl_down(s, d, 64); q += __shfl_down(q, d, 64); }
    __shared__ float rs[4], rq[4];
    int wave = t >> 6, lane = t & 63;
    if (lane == 0) { rs[wave] = s; rq[wave] = q; }
    __syncthreads();
    if (t == 0) {
        float S = rs[0] + rs[1] + rs[2] + rs[3];
        float Q = rq[0] + rq[1] + rq[2] + rq[3];
        const float inv = 1.0f / 65536.0f;
        float mean = S * inv;
        float var = Q * inv - mean * mean;
        float sc = gamma[o] * rsqrtf(var + 1e-5f);
        ss[o] = sc;
        ss[NC + o] = beta[o] - mean * sc;
    }
}

// out = wz*scale + shift + x  (wz bf16, x f32 -> out f32)
__global__ void k_apply(float* __restrict__ out, const ushort* __restrict__ wz,
        const float* __restrict__ x, const float* __restrict__ ss) {
    size_t i = ((size_t)blockIdx.x * 256 + threadIdx.x) * 8;
    int o = (int)((i >> 12) & 255);
    float sc = ss[o], sh = ss[NC + o];
    uint4 wv = *(const uint4*)(wz + i);
    float4 x0 = *(const float4*)(x + i);
    float4 x1 = *(const float4*)(x + i + 4);
    float4 r0, r1;
    r0.x = b2f_lo(wv.x) * sc + sh + x0.x;
    r0.y = b2f_hi(wv.x) * sc + sh + x0.y;
    r0.z = b2f_lo(wv.y) * sc + sh + x0.z;
    r0.w = b2f_hi(wv.y) * sc + sh + x0.w;
    r1.x = b2f_lo(wv.z) * sc + sh + x1.x;
    r1.y = b2f_hi(wv.z) * sc + sh + x1.y;
    r1.z = b2f_lo(wv.w) * sc + sh + x1.z;
    r1.w = b2f_hi(wv.w) * sc + sh + x1.w;
    *(float4*)(out + i) = r0;
    *(float4*)(out + i + 4) = r1;
}

extern "C" void kernel_launch(void* const* d_in, const int* in_sizes, int n_in,
                              void* d_out, int out_size, void* d_ws, size_t ws_size,
                              hipStream_t stream) {
    const float* x       = (const float*)d_in[0];
    const float* y       = (const float*)d_in[1];
    const float* theta_w = (const float*)d_in[2];
    const float* theta_b = (const float*)d_in[3];
    const float* phi_w   = (const float*)d_in[4];
    const float* phi_b   = (const float*)d_in[5];
    const float* g_w     = (const float*)d_in[6];
    const float* g_b     = (const float*)d_in[7];
    const float* W_w     = (const float*)d_in[8];
    const float* W_b     = (const float*)d_in[9];
    const float* bn_g    = (const float*)d_in[10];
    const float* bn_b    = (const float*)d_in[11];
    float* ws  = (float*)d_ws;
    float* out = (float*)d_out;

    // ws layout (float offsets):
    //   [0,        65536)    wbf: 4x32768 bf16 weights
    //   [65536,    4259840)  thetaT bf16 [16][4096][128]   (dead after attn)
    //   [65536,    8454144)  wzbf bf16 [16][256][4096]     (written by k_wz after attn)
    //   [8454144, 12648448)  z bf16 [16][4096][128]        (attn out; DISJOINT from wzbf)
    //   [12648448,13697024)  phiT bf16 [16][1024][128]
    //   [13697024,14745600)  gbuf bf16 [16][128][1024]
    //   [14745600,15269888)  part [1024][512]
    //   [15269888,15270400)  ss
    ushort* wbf    = (ushort*)ws;
    ushort* thetaT = (ushort*)(ws + 65536);
    ushort* wzbf   = (ushort*)(ws + 65536);
    ushort* zbuf   = (ushort*)(ws + 8454144);
    ushort* phiT   = (ushort*)(ws + 12648448);
    ushort* gbuf   = (ushort*)(ws + 13697024);
    float*  part   = ws + 14745600;
    float*  ss     = ws + 15269888;

    k_castw<<<dim3(16, 4), 256, 0, stream>>>(theta_w, phi_w, g_w, W_w, wbf);

    k_conv_mfma<128, 128><<<NB * 32, 256, 0, stream>>>(x, wbf, theta_b, theta_b, thetaT);
    k_convpool<<<NB * 32, 512, 0, stream>>>(y, wbf + 32768, phi_b, g_b, phiT, gbuf);

    k_attn_mfma<<<NB * 16, 512, 0, stream>>>(thetaT, phiT, gbuf, zbuf);

    k_wz_mfma<<<dim3(NB * 32, 2), 256, 0, stream>>>(zbuf, wbf + 98304, W_b, wzbf, part);
    k_bnstats<<<256, 256, 0, stream>>>(part, bn_g, bn_b, ss);
    k_apply<<<8192, 256, 0, stream>>>(out, wzbf, x, ss);
}